// Round 1
// baseline (444.386 us; speedup 1.0000x reference)
//
#include <hip/hip_runtime.h>
#include <math.h>

#define T_TOK 16384
#define D_DIM 2048
#define NSLOT 64
#define H_DIM 1024

// ---------------------------------------------------------------------------
// Kernel 1: logits[t][s] = dot(x[t,:], Wd[s,:])   (T x 64)
// block 256, grid T/32. Tile 32 tokens x 64 slots, K-chunks of 64.
// ---------------------------------------------------------------------------
__global__ __launch_bounds__(256) void k_logits(const float* __restrict__ x,
                                                const float* __restrict__ Wd,
                                                float* __restrict__ logits) {
    __shared__ float xs[32][68];
    __shared__ float ws[64][68];
    const int tid = threadIdx.x;
    const int tblk = blockIdx.x * 32;
    const int sb = tid & 15;        // slot lane: slots sb + j*16
    const int t0 = (tid >> 4) * 2;  // 2 tokens per thread
    float acc[2][4] = {};

    for (int k0 = 0; k0 < D_DIM; k0 += 64) {
        // stage x tile: 32 rows x 64 cols = 512 float4
        #pragma unroll
        for (int i = 0; i < 2; ++i) {
            int fi = tid + i * 256;
            int r = fi >> 4, c4 = fi & 15;
            *(float4*)&xs[r][c4 * 4] =
                *(const float4*)&x[(size_t)(tblk + r) * D_DIM + k0 + c4 * 4];
        }
        // stage W tile: 64 rows x 64 cols = 1024 float4
        #pragma unroll
        for (int i = 0; i < 4; ++i) {
            int fi = tid + i * 256;
            int r = fi >> 4, c4 = fi & 15;
            *(float4*)&ws[r][c4 * 4] =
                *(const float4*)&Wd[(size_t)r * D_DIM + k0 + c4 * 4];
        }
        __syncthreads();
        #pragma unroll
        for (int k = 0; k < 64; k += 4) {
            float4 xv[2], wv[4];
            #pragma unroll
            for (int i = 0; i < 2; ++i) xv[i] = *(const float4*)&xs[t0 + i][k];
            #pragma unroll
            for (int j = 0; j < 4; ++j) wv[j] = *(const float4*)&ws[sb + j * 16][k];
            #pragma unroll
            for (int i = 0; i < 2; ++i)
                #pragma unroll
                for (int j = 0; j < 4; ++j)
                    acc[i][j] += xv[i].x * wv[j].x + xv[i].y * wv[j].y +
                                 xv[i].z * wv[j].z + xv[i].w * wv[j].w;
        }
        __syncthreads();
    }
    #pragma unroll
    for (int i = 0; i < 2; ++i)
        #pragma unroll
        for (int j = 0; j < 4; ++j)
            logits[(size_t)(tblk + t0 + i) * NSLOT + sb + j * 16] = acc[i][j];
}

// ---------------------------------------------------------------------------
// Kernel 2: per-(block,slot) partial column max / sum-exp. grid 64, block 256.
// Block b covers tokens [b*256, b*256+256). Thread's slot is tid&63 by layout.
// ---------------------------------------------------------------------------
__global__ __launch_bounds__(256) void k_cred1(const float* __restrict__ logits,
                                               float* __restrict__ pm,
                                               float* __restrict__ pz) {
    __shared__ float lm[256], lz[256];
    const int tid = threadIdx.x;
    const size_t base = (size_t)blockIdx.x * 256 * NSLOT;
    float m = -1e30f, z = 0.f;
    for (int i = 0; i < 64; ++i) {
        float v = logits[base + (size_t)i * 256 + tid];
        float nm = fmaxf(m, v);
        z = z * __expf(m - nm) + __expf(v - nm);
        m = nm;
    }
    lm[tid] = m; lz[tid] = z;
    __syncthreads();
    if (tid < 64) {
        float M = lm[tid], Z = lz[tid];
        #pragma unroll
        for (int i = 1; i < 4; ++i) {
            float m2 = lm[tid + i * 64], z2 = lz[tid + i * 64];
            float nm = fmaxf(M, m2);
            Z = Z * __expf(M - nm) + z2 * __expf(m2 - nm);
            M = nm;
        }
        pm[blockIdx.x * NSLOT + tid] = M;
        pz[blockIdx.x * NSLOT + tid] = Z;
    }
}

// Kernel 3: final column softmax stats. 1 block, 64 threads.
__global__ void k_cred2(const float* __restrict__ pm, const float* __restrict__ pz,
                        float* __restrict__ m_out, float* __restrict__ invZ_out) {
    const int s = threadIdx.x;
    float M = -1e30f, Z = 0.f;
    for (int i = 0; i < 64; ++i) {
        float m2 = pm[i * NSLOT + s], z2 = pz[i * NSLOT + s];
        float nm = fmaxf(M, m2);
        Z = Z * __expf(M - nm) + z2 * __expf(m2 - nm);
        M = nm;
    }
    m_out[s] = M;
    invZ_out[s] = 1.f / Z;
}

// ---------------------------------------------------------------------------
// Kernel 4: partial slot_inputs. grid (16 d-tiles, 32 t-chunks), block 256.
// partial[chunk][s][d] = sum over 512 tokens of dispatch[t][s] * x[t][d]
// ---------------------------------------------------------------------------
__global__ __launch_bounds__(256) void k_slot_inputs(const float* __restrict__ x,
        const float* __restrict__ logits, const float* __restrict__ mS,
        const float* __restrict__ invZ, float* __restrict__ partial) {
    __shared__ float xs[64][128];
    __shared__ float pls[64][64];
    __shared__ float ms[64], zs[64];
    const int tid = threadIdx.x;
    const int d0 = blockIdx.x * 128;
    const int tc0 = blockIdx.y * 512;
    if (tid < 64) { ms[tid] = mS[tid]; zs[tid] = invZ[tid]; }
    const int g = tid & 31;        // float4 column
    const int s0 = (tid >> 5) * 8; // 8 slots per thread
    float4 acc[8] = {};

    for (int sub = 0; sub < 8; ++sub) {
        const int t0 = tc0 + sub * 64;
        __syncthreads();
        #pragma unroll
        for (int i = 0; i < 8; ++i) {
            int fi = tid + i * 256;
            int r = fi >> 5, c4 = fi & 31;
            *(float4*)&xs[r][c4 * 4] =
                *(const float4*)&x[(size_t)(t0 + r) * D_DIM + d0 + c4 * 4];
        }
        #pragma unroll
        for (int i = 0; i < 16; ++i) {
            int fi = tid + i * 256;
            int r = fi >> 6, s = fi & 63;
            float lv = logits[(size_t)(t0 + r) * NSLOT + s];
            pls[r][s] = __expf(lv - ms[s]) * zs[s];
        }
        __syncthreads();
        for (int t = 0; t < 64; ++t) {
            float4 xv = *(const float4*)&xs[t][g * 4];
            #pragma unroll
            for (int i = 0; i < 8; ++i) {
                float p = pls[t][s0 + i];
                acc[i].x += p * xv.x; acc[i].y += p * xv.y;
                acc[i].z += p * xv.z; acc[i].w += p * xv.w;
            }
        }
    }
    #pragma unroll
    for (int i = 0; i < 8; ++i) {
        int s = s0 + i;
        *(float4*)&partial[((size_t)blockIdx.y * NSLOT + s) * D_DIM + d0 + g * 4] = acc[i];
    }
}

// Kernel 5: reduce 32 t-chunk partials -> slot_in (64 x 2048). grid 128, blk 256.
__global__ __launch_bounds__(256) void k_sred(const float* __restrict__ partial,
                                              float* __restrict__ slot_in) {
    const int idx = blockIdx.x * 256 + threadIdx.x;  // float4 index, < 32768
    float4 a = {0.f, 0.f, 0.f, 0.f};
    for (int c = 0; c < 32; ++c) {
        float4 v = *(const float4*)&partial[(size_t)c * (NSLOT * D_DIM) + (size_t)idx * 4];
        a.x += v.x; a.y += v.y; a.z += v.z; a.w += v.w;
    }
    *(float4*)&slot_in[(size_t)idx * 4] = a;
}

// ---------------------------------------------------------------------------
// Kernel 6: h[e][j] = gelu(dot(W1[e][j,:], slot_in[e,:]) + b1[e][j])
// one wave per row; grid 65536/4 blocks of 256.
// ---------------------------------------------------------------------------
__global__ __launch_bounds__(256) void k_mlp1(const float* __restrict__ W1,
                                              const float* __restrict__ b1,
                                              const float* __restrict__ slot_in,
                                              float* __restrict__ h) {
    const int wave = threadIdx.x >> 6, lane = threadIdx.x & 63;
    const int row = blockIdx.x * 4 + wave;           // e*1024 + j
    const int e = row >> 10;
    const float* wr = W1 + (size_t)row * D_DIM;
    const float* xr = slot_in + (size_t)e * D_DIM;
    float acc = 0.f;
    #pragma unroll
    for (int i = 0; i < 8; ++i) {
        int k = (lane + i * 64) * 4;
        float4 w4 = *(const float4*)(wr + k);
        float4 x4 = *(const float4*)(xr + k);
        acc += w4.x * x4.x + w4.y * x4.y + w4.z * x4.z + w4.w * x4.w;
    }
    #pragma unroll
    for (int off = 32; off; off >>= 1) acc += __shfl_xor(acc, off);
    if (lane == 0) {
        float v = acc + b1[row];
        h[row] = 0.5f * v * (1.f + erff(v * 0.70710678118654752f));
    }
}

// Kernel 7: slot_out[e][d] = dot(W2[e][d,:], h[e,:]) + b2[e][d]
// one wave per row; grid 131072/4 blocks of 256.
__global__ __launch_bounds__(256) void k_mlp2(const float* __restrict__ W2,
                                              const float* __restrict__ b2,
                                              const float* __restrict__ h,
                                              float* __restrict__ slot_out) {
    const int wave = threadIdx.x >> 6, lane = threadIdx.x & 63;
    const int row = blockIdx.x * 4 + wave;           // e*2048 + d
    const int e = row >> 11;
    const float* wr = W2 + (size_t)row * H_DIM;
    const float* xr = h + (size_t)e * H_DIM;
    float acc = 0.f;
    #pragma unroll
    for (int i = 0; i < 4; ++i) {
        int k = (lane + i * 64) * 4;
        float4 w4 = *(const float4*)(wr + k);
        float4 x4 = *(const float4*)(xr + k);
        acc += w4.x * x4.x + w4.y * x4.y + w4.z * x4.z + w4.w * x4.w;
    }
    #pragma unroll
    for (int off = 32; off; off >>= 1) acc += __shfl_xor(acc, off);
    if (lane == 0) slot_out[row] = acc + b2[row];
}

// ---------------------------------------------------------------------------
// Kernel 8: y[t][d] = sum_s softmax_row(logits)[t][s] * slot_out[s][d]
// grid (16 d-tiles of 128, 256 t-tiles of 64), block 256.
// ---------------------------------------------------------------------------
__global__ __launch_bounds__(256) void k_combine(const float* __restrict__ logits,
                                                 const float* __restrict__ so,
                                                 float* __restrict__ y) {
    __shared__ float cl[64][65];
    __shared__ float sol[64][128];
    const int tid = threadIdx.x;
    const int d0 = blockIdx.x * 128;
    const int tb = blockIdx.y * 64;
    // stage logits 64x64
    #pragma unroll
    for (int i = 0; i < 16; ++i) {
        int fi = tid + i * 256;
        int r = fi >> 6, s = fi & 63;
        cl[r][s] = logits[(size_t)(tb + r) * NSLOT + s];
    }
    // stage slot_out tile 64x128
    #pragma unroll
    for (int i = 0; i < 8; ++i) {
        int fi = tid + i * 256;
        int r = fi >> 5, c4 = fi & 31;
        *(float4*)&sol[r][c4 * 4] =
            *(const float4*)&so[(size_t)r * D_DIM + d0 + c4 * 4];
    }
    __syncthreads();
    // row softmax (wave 0, one token per lane)
    if (tid < 64) {
        float M = -1e30f;
        for (int s = 0; s < 64; ++s) M = fmaxf(M, cl[tid][s]);
        float Z = 0.f;
        for (int s = 0; s < 64; ++s) { float e = __expf(cl[tid][s] - M); cl[tid][s] = e; Z += e; }
        float r = 1.f / Z;
        for (int s = 0; s < 64; ++s) cl[tid][s] *= r;
    }
    __syncthreads();
    const int g0 = tid & 15;       // float4 col base; cols g0 + j*16
    const int t0 = (tid >> 4) * 4; // 4 tokens per thread
    float4 acc[4][2] = {};
    for (int s = 0; s < 64; ++s) {
        float4 sv[2];
        float cv[4];
        #pragma unroll
        for (int j = 0; j < 2; ++j) sv[j] = *(const float4*)&sol[s][(g0 + j * 16) * 4];
        #pragma unroll
        for (int i = 0; i < 4; ++i) cv[i] = cl[t0 + i][s];
        #pragma unroll
        for (int i = 0; i < 4; ++i)
            #pragma unroll
            for (int j = 0; j < 2; ++j) {
                acc[i][j].x += cv[i] * sv[j].x; acc[i][j].y += cv[i] * sv[j].y;
                acc[i][j].z += cv[i] * sv[j].z; acc[i][j].w += cv[i] * sv[j].w;
            }
    }
    #pragma unroll
    for (int i = 0; i < 4; ++i)
        #pragma unroll
        for (int j = 0; j < 2; ++j)
            *(float4*)&y[(size_t)(tb + t0 + i) * D_DIM + d0 + (g0 + j * 16) * 4] = acc[i][j];
}

// ---------------------------------------------------------------------------
extern "C" void kernel_launch(void* const* d_in, const int* in_sizes, int n_in,
                              void* d_out, int out_size, void* d_ws, size_t ws_size,
                              hipStream_t stream) {
    const float* x  = (const float*)d_in[0];
    const float* Wd = (const float*)d_in[1];
    const float* W1 = (const float*)d_in[2];
    const float* b1 = (const float*)d_in[3];
    const float* W2 = (const float*)d_in[4];
    const float* b2 = (const float*)d_in[5];
    float* y = (float*)d_out;

    float* w = (float*)d_ws;
    float* logits  = w;                         // 16384*64   = 1,048,576
    float* pm      = logits + (size_t)T_TOK * NSLOT;       // 4096
    float* pz      = pm + 64 * NSLOT;                      // 4096
    float* mS      = pz + 64 * NSLOT;                      // 64
    float* invZ    = mS + NSLOT;                           // 64
    float* partial = invZ + NSLOT;                         // 32*64*2048 = 4,194,304
    float* slot_in = partial + (size_t)32 * NSLOT * D_DIM; // 131,072
    float* h       = slot_in + (size_t)NSLOT * D_DIM;      // 65,536
    float* slot_out= h + (size_t)NSLOT * H_DIM;            // 131,072

    k_logits<<<T_TOK / 32, 256, 0, stream>>>(x, Wd, logits);
    k_cred1<<<64, 256, 0, stream>>>(logits, pm, pz);
    k_cred2<<<1, 64, 0, stream>>>(pm, pz, mS, invZ);
    k_slot_inputs<<<dim3(16, 32), 256, 0, stream>>>(x, logits, mS, invZ, partial);
    k_sred<<<128, 256, 0, stream>>>(partial, slot_in);
    k_mlp1<<<(NSLOT * H_DIM) / 4, 256, 0, stream>>>(W1, b1, slot_in, h);
    k_mlp2<<<(NSLOT * D_DIM) / 4, 256, 0, stream>>>(W2, b2, h, slot_out);
    k_combine<<<dim3(16, 256), 256, 0, stream>>>(logits, slot_out, y);
}